// Round 3
// baseline (20.890 us; speedup 1.0000x reference)
//
#include <hip/hip_runtime.h>
#include <hip/hip_bf16.h>

#define BATCH   1024
#define IN_DIM  256
#define UNITS   256

using short8 = __attribute__((ext_vector_type(8))) short;
using f32x4  = __attribute__((ext_vector_type(4))) float;

// Padded feature space: 16 features per input dim i (kf 0..7 bases, 8 silu, 9..15 zero)
// K = 256*16 = 4096.  Wp layout: [nt=16][S=128][lane=64][e=8] bf16 (2 MB)
#define WP_ELEMS (16 * 128 * 512)

__device__ __forceinline__ unsigned short f2bf(float v) {
    __hip_bfloat16 h = __float2bfloat16(v);
    return *reinterpret_cast<unsigned short*>(&h);
}

// ---------------- prep W: W'[k,o]; k=16i+kf: kf<8 -> SK[i,kf,o]*SF[i,o],
//                  kf==8 -> SF[i,o], kf>8 -> 0.  Fragment-packed. ------------
__global__ __launch_bounds__(256) void prep_w(const float* __restrict__ SK,
                                              const float* __restrict__ SF,
                                              unsigned short* __restrict__ Wp) {
    const int slot = blockIdx.x * 256 + threadIdx.x;   // < 131072
    const int lane = slot & 63;
    const int S    = (slot >> 6) & 127;
    const int nt   = slot >> 13;
    const int o    = nt * 16 + (lane & 15);
    const int kb   = S * 32 + ((lane >> 4) << 3);      // 8-aligned
    const int i    = kb >> 4;
    const float sfv = SF[i * UNITS + o];
    unsigned short r[8];
    if ((kb & 15) == 0) {                               // kf 0..7: bases * sf
        #pragma unroll
        for (int e = 0; e < 8; ++e)
            r[e] = f2bf(SK[(i * 8 + e) * UNITS + o] * sfv);
    } else {                                            // kf 8..15: silu coeff, zeros
        r[0] = f2bf(sfv);
        #pragma unroll
        for (int e = 1; e < 8; ++e) r[e] = 0;
    }
    unsigned int pk[4];
    #pragma unroll
    for (int e = 0; e < 4; ++e)
        pk[e] = (unsigned int)r[2 * e] | ((unsigned int)r[2 * e + 1] << 16);
    reinterpret_cast<uint4*>(Wp)[slot] = make_uint4(pk[0], pk[1], pk[2], pk[3]);
}

// ---------------- fused GEMM: 256 blocks x 512 thr; tile 32x32; 8-way split-K.
// Wave w owns i in [32w,32w+32) (k in [512w,512w+512)); computes features into
// a wave-private 4KB LDS fragment region (reused over 8 passes of 2 K-steps).
__global__ __launch_bounds__(512, 2) void kan_gemm_fused(
    const float* __restrict__ X,
    const unsigned short* __restrict__ Wp,
    const float* __restrict__ BIAS,
    float* __restrict__ OUT) {
    __shared__ __align__(16) unsigned char smem[32768];
    unsigned short* feat = (unsigned short*)smem;
    const int tid  = threadIdx.x;
    const int w    = tid >> 6;
    const int lane = tid & 63;
    const int m = blockIdx.x & 31;
    const int n = blockIdx.x >> 5;

    // one-time zero of own wave region (covers the kf 9..15 zero slots)
    {
        short8 z = {0, 0, 0, 0, 0, 0, 0, 0};
        short8* fz = (short8*)(feat + w * 2048);
        #pragma unroll
        for (int zz = 0; zz < 4; ++zz) fz[zz * 64 + lane] = z;
    }

    f32x4 acc00 = {0.f,0.f,0.f,0.f}, acc01 = {0.f,0.f,0.f,0.f};
    f32x4 acc10 = {0.f,0.f,0.f,0.f}, acc11 = {0.f,0.f,0.f,0.f};
    const short8* B8  = (const short8*)Wp;
    const short8* bp0 = B8 + ((size_t)(2 * n)     * 128 + w * 16) * 64 + lane;
    const short8* bp1 = B8 + ((size_t)(2 * n + 1) * 128 + w * 16) * 64 + lane;
    const unsigned short* fr = feat + w * 2048;

    #pragma unroll
    for (int p = 0; p < 8; ++p) {
        // ---- feature phase: 4 i x 32 rows, 2 x per lane ----
        #pragma unroll
        for (int t = 0; t < 2; ++t) {
            const int idx = t * 64 + lane;
            const int row = idx & 31;
            const int il4 = idx >> 5;                 // 0..3
            const int i   = w * 32 + p * 4 + il4;
            const float x = X[(m * 32 + row) * IN_DIM + i];
            const float u = (x + 2.2f) * 2.5f;
            int j = (int)floorf(u);
            j = j < 3 ? 3 : (j > 7 ? 7 : j);
            const float gj = -2.2f + 0.4f * (float)j;
            const float tt = (x - gj) * 2.5f;
            const float t2 = tt * tt, t3 = t2 * tt;
            const float s1 = 1.f - tt;
            const float b0 = s1 * s1 * s1 * (1.f / 6.f);
            const float b1 = fmaf(0.5f, t3, fmaf(-1.f, t2, 2.f / 3.f));
            const float b3 = t3 * (1.f / 6.f);
            const float b2 = 1.f - b0 - b1 - b3;      // partition of unity
            const float sil = x / (1.f + __expf(-x));
            // fragment slot: s_loc = il4>>1, rowgroup = row>>4,
            // lane_t = (row&15) | ((il4&1)<<5)  (bases kgroup), silu at lane_t+16
            unsigned short* sp = feat + w * 2048 + (il4 >> 1) * 1024 +
                                 (row >> 4) * 512 +
                                 (((row & 15) | ((il4 & 1) << 5)) << 3);
            short8 z = {0, 0, 0, 0, 0, 0, 0, 0};
            *(short8*)sp = z;                          // clear stale bases slot
            const int base = j - 3;                    // 0..4
            sp[base + 0] = f2bf(b0);
            sp[base + 1] = f2bf(b1);
            sp[base + 2] = f2bf(b2);
            sp[base + 3] = f2bf(b3);
            sp[128]      = f2bf(sil);                  // kgroup+1, e=0
        }
        // ---- MFMA phase: 2 K-steps (wave-local LDS, no barrier) ----
        #pragma unroll
        for (int s = 0; s < 2; ++s) {
            short8 a0 = *(const short8*)(fr + s * 1024 + lane * 8);
            short8 a1 = *(const short8*)(fr + s * 1024 + 512 + lane * 8);
            short8 b0 = bp0[(p * 2 + s) * 64];
            short8 b1 = bp1[(p * 2 + s) * 64];
            acc00 = __builtin_amdgcn_mfma_f32_16x16x32_bf16(a0, b0, acc00, 0, 0, 0);
            acc01 = __builtin_amdgcn_mfma_f32_16x16x32_bf16(a0, b1, acc01, 0, 0, 0);
            acc10 = __builtin_amdgcn_mfma_f32_16x16x32_bf16(a1, b0, acc10, 0, 0, 0);
            acc11 = __builtin_amdgcn_mfma_f32_16x16x32_bf16(a1, b1, acc11, 0, 0, 0);
        }
    }

    // ---- split-K reduce (wave writes its own region; one barrier) ----
    f32x4* redv = (f32x4*)smem;
    redv[(w * 4 + 0) * 64 + lane] = acc00;
    redv[(w * 4 + 1) * 64 + lane] = acc01;
    redv[(w * 4 + 2) * 64 + lane] = acc10;
    redv[(w * 4 + 3) * 64 + lane] = acc11;
    __syncthreads();
    const float* red = (const float*)smem;
    #pragma unroll
    for (int half = 0; half < 2; ++half) {
        const int flat = half * 512 + tid;
        float sum = 0.f;
        #pragma unroll
        for (int w2 = 0; w2 < 8; ++w2) sum += red[w2 * 1024 + flat];
        const int f  = flat >> 8;
        const int l  = (flat >> 2) & 63;
        const int rr = flat & 3;
        const int row = m * 32 + (f >> 1) * 16 + ((l >> 4) << 2) + rr;
        const int col = n * 32 + (f & 1) * 16 + (l & 15);
        OUT[row * UNITS + col] = sum + BIAS[col];
    }
}

// ---------------- fallback (round-1 fused fp32, no workspace) ----------------
__global__ __launch_bounds__(256) void kan_fused(
    const float* __restrict__ X, const float* __restrict__ SK,
    const float* __restrict__ SF, const float* __restrict__ BIAS,
    float* __restrict__ OUT) {
    __shared__ float feat[128][12];
    const int tid  = threadIdx.x;
    const int brow = blockIdx.x * 4;
    const int o    = tid;
    float acc[4] = {0.f, 0.f, 0.f, 0.f};
    for (int c = 0; c < 8; ++c) {
        if (tid < 128) {
            const int ii = tid >> 2;
            const int r  = tid & 3;
            const int i  = c * 32 + ii;
            const float x = X[(size_t)(brow + r) * IN_DIM + i];
            float u = (x + 2.2f) * 2.5f;
            int j = (int)floorf(u);
            j = j < 3 ? 3 : (j > 7 ? 7 : j);
            const float gj = -2.2f + 0.4f * (float)j;
            const float t  = (x - gj) * 2.5f;
            const float t2 = t * t, t3 = t2 * t;
            const float k6 = 1.f / 6.f;
            float* fp = feat[ii * 4 + r];
            #pragma unroll
            for (int k = 0; k < 12; ++k) fp[k] = 0.f;
            const int base = j - 3;
            fp[base + 0] = (1.f - 3.f*t + 3.f*t2 - t3) * k6;
            fp[base + 1] = (3.f*t3 - 6.f*t2 + 4.f) * k6;
            fp[base + 2] = (-3.f*t3 + 3.f*t2 + 3.f*t + 1.f) * k6;
            fp[base + 3] = t3 * k6;
            fp[8] = x / (1.f + __expf(-x));
        }
        __syncthreads();
        #pragma unroll 4
        for (int ii = 0; ii < 32; ++ii) {
            const int i = c * 32 + ii;
            const float* skp = SK + (size_t)i * 8 * UNITS + o;
            const float s0 = skp[0*UNITS], s1 = skp[1*UNITS], s2 = skp[2*UNITS], s3 = skp[3*UNITS];
            const float s4 = skp[4*UNITS], s5 = skp[5*UNITS], s6 = skp[6*UNITS], s7 = skp[7*UNITS];
            const float sfv = SF[(size_t)i * UNITS + o];
            #pragma unroll
            for (int r = 0; r < 4; ++r) {
                const float* fp = feat[ii * 4 + r];
                const float4 fa = *(const float4*)(fp);
                const float4 fb = *(const float4*)(fp + 4);
                float ts = fp[8];
                ts = fmaf(fa.x, s0, ts); ts = fmaf(fa.y, s1, ts);
                ts = fmaf(fa.z, s2, ts); ts = fmaf(fa.w, s3, ts);
                ts = fmaf(fb.x, s4, ts); ts = fmaf(fb.y, s5, ts);
                ts = fmaf(fb.z, s6, ts); ts = fmaf(fb.w, s7, ts);
                acc[r] = fmaf(sfv, ts, acc[r]);
            }
        }
        __syncthreads();
    }
    const float bo = BIAS[o];
    #pragma unroll
    for (int r = 0; r < 4; ++r)
        OUT[(size_t)(brow + r) * UNITS + o] = acc[r] + bo;
}

extern "C" void kernel_launch(void* const* d_in, const int* in_sizes, int n_in,
                              void* d_out, int out_size, void* d_ws, size_t ws_size,
                              hipStream_t stream) {
    const float* X  = (const float*)d_in[0];
    const float* SK = (const float*)d_in[1];
    const float* SF = (const float*)d_in[2];
    const float* B  = (const float*)d_in[3];
    float* OUT = (float*)d_out;

    const size_t need = (size_t)WP_ELEMS * 2;   // 2 MB
    if (d_ws != nullptr && ws_size >= need) {
        unsigned short* Wp = (unsigned short*)d_ws;
        prep_w<<<dim3(512), dim3(256), 0, stream>>>(SK, SF, Wp);
        kan_gemm_fused<<<dim3(256), dim3(512), 0, stream>>>(X, Wp, B, OUT);
    } else {
        kan_fused<<<dim3(BATCH / 4), dim3(256), 0, stream>>>(X, SK, SF, B, OUT);
    }
}

// Round 4
// 17.079 us; speedup vs baseline: 1.2232x; 1.2232x over previous
//
#include <hip/hip_runtime.h>
#include <hip/hip_bf16.h>

#define BATCH   1024
#define IN_DIM  256
#define UNITS   256

using short8 = __attribute__((ext_vector_type(8))) short;
using f32x4  = __attribute__((ext_vector_type(4))) float;

// A_p: [mt=64][s=72][lane=64][e=8] bf16   (M=1024 rows /16, K=2304 /32)
// W_p: [nt=16][s=72][lane=64][e=8] bf16   (N=256 cols /16)
#define A_ELEMS (64 * 72 * 512)   // 2,359,296 ushort
#define W_ELEMS (16 * 72 * 512)   //   589,824 ushort

__device__ __forceinline__ unsigned short f2bf(float v) {
    __hip_bfloat16 h = __float2bfloat16(v);
    return *reinterpret_cast<unsigned short*>(&h);
}

// ---------------- combined prep: blocks [0,256) do A, [256,544) do W --------
// A part: grid-split (mt 64) x (quarter q 4); rows mt*16..+16, i in [64q,64q+64)
// W part: one thread per 16B fragment slot (73728 slots = 288 blocks x 256)
__global__ __launch_bounds__(256) void prep_all(const float* __restrict__ X,
                                                const float* __restrict__ SK,
                                                const float* __restrict__ SF,
                                                unsigned short* __restrict__ Ap,
                                                unsigned short* __restrict__ Wp) {
    const int t = threadIdx.x;
    if (blockIdx.x < 256) {
        __shared__ unsigned short tile[18 * 512];
        const int mt = blockIdx.x >> 2;
        const int q  = blockIdx.x & 3;
        #pragma unroll
        for (int rr = 0; rr < 4; ++rr) {
            const int p  = t + 256 * rr;
            const int b  = p >> 6;
            const int il = p & 63;
            const int i  = q * 64 + il;
            const float x = X[(mt * 16 + b) * IN_DIM + i];
            const float u = (x + 2.2f) * 2.5f;
            int j = (int)floorf(u);
            j = j < 3 ? 3 : (j > 7 ? 7 : j);
            const float gj = -2.2f + 0.4f * (float)j;
            const float tt = (x - gj) * 2.5f;
            const float t2 = tt * tt, t3 = t2 * tt;
            const float k6 = 1.f / 6.f;
            const float b0 = (1.f - 3.f * tt + 3.f * t2 - t3) * k6;
            const float b1 = (3.f * t3 - 6.f * t2 + 4.f) * k6;
            const float b2 = (-3.f * t3 + 3.f * t2 + 3.f * tt + 1.f) * k6;
            const float b3 = t3 * k6;
            const float sil = x / (1.f + __expf(-x));
            const int base = j - 3;
            const int kk0  = il * 9;
            #pragma unroll
            for (int kf = 0; kf < 9; ++kf) {
                float v;
                if (kf == 8) v = sil;
                else v = (kf == base)     ? b0
                       : (kf == base + 1) ? b1
                       : (kf == base + 2) ? b2
                       : (kf == base + 3) ? b3 : 0.f;
                const int kkl  = kk0 + kf;
                const int sl   = kkl >> 5;
                const int kpos = kkl & 31;
                tile[sl * 512 + ((b | ((kpos >> 3) << 4)) << 3) + (kpos & 7)] = f2bf(v);
            }
        }
        __syncthreads();
        const unsigned int* src = (const unsigned int*)tile;
        unsigned int* dst = (unsigned int*)Ap + (mt * 72 + 18 * q) * 256;
        #pragma unroll
        for (int k = 0; k < 18; ++k) dst[t + 256 * k] = src[t + 256 * k];
    } else {
        const int slot = (blockIdx.x - 256) * 256 + t;   // < 73728
        const int lane = slot & 63;
        const int s    = (slot >> 6) % 72;
        const int nt   = slot / (72 * 64);
        const int o    = nt * 16 + (lane & 15);
        const int kb   = (lane >> 4) << 3;
        unsigned short r[8];
        #pragma unroll
        for (int e = 0; e < 8; ++e) {
            const int kk = s * 32 + kb + e;   // 0..2303
            const int i  = kk / 9;
            const int kf = kk - i * 9;
            const float sfv = SF[i * UNITS + o];
            const float v = (kf < 8) ? SK[(i * 8 + kf) * UNITS + o] * sfv : sfv;
            r[e] = f2bf(v);
        }
        unsigned int pack[4];
        #pragma unroll
        for (int e = 0; e < 4; ++e)
            pack[e] = (unsigned int)r[2 * e] | ((unsigned int)r[2 * e + 1] << 16);
        reinterpret_cast<uint4*>(Wp)[slot] = make_uint4(pack[0], pack[1], pack[2], pack[3]);
    }
}

// ---------------- GEMM: 256 blocks x 512 thr; tile 32x32, K split 8 ----
__global__ __launch_bounds__(512) void kan_gemm(const unsigned short* __restrict__ Ap,
                                                const unsigned short* __restrict__ Wp,
                                                const float* __restrict__ BIAS,
                                                float* __restrict__ OUT) {
    __shared__ float red[8 * 1024];    // 32 KB: [wave][frag4][lane][4]
    const int tid  = threadIdx.x;
    const int w    = tid >> 6;
    const int lane = tid & 63;
    const int m = blockIdx.x & 31;     // same-m blocks land on same XCD (32n = 0 mod 8)
    const int n = blockIdx.x >> 5;
    const short8* A8 = (const short8*)Ap;
    const short8* W8 = (const short8*)Wp;
    const int mt0 = 2 * m, nt0 = 2 * n;
    const int s0  = 9 * w;

    const short8* pa0 = A8 + (size_t)(mt0 * 72 + s0) * 64 + lane;
    const short8* pa1 = pa0 + 72 * 64;
    const short8* pb0 = W8 + (size_t)(nt0 * 72 + s0) * 64 + lane;
    const short8* pb1 = pb0 + 72 * 64;

    f32x4 acc00 = {0.f, 0.f, 0.f, 0.f}, acc01 = {0.f, 0.f, 0.f, 0.f};
    f32x4 acc10 = {0.f, 0.f, 0.f, 0.f}, acc11 = {0.f, 0.f, 0.f, 0.f};

    short8 a0 = pa0[0], a1 = pa1[0], b0 = pb0[0], b1 = pb1[0];
    #pragma unroll
    for (int it = 0; it < 9; ++it) {
        acc00 = __builtin_amdgcn_mfma_f32_16x16x32_bf16(a0, b0, acc00, 0, 0, 0);
        acc01 = __builtin_amdgcn_mfma_f32_16x16x32_bf16(a0, b1, acc01, 0, 0, 0);
        acc10 = __builtin_amdgcn_mfma_f32_16x16x32_bf16(a1, b0, acc10, 0, 0, 0);
        acc11 = __builtin_amdgcn_mfma_f32_16x16x32_bf16(a1, b1, acc11, 0, 0, 0);
        if (it < 8) {
            a0 = pa0[64 * (it + 1)];
            a1 = pa1[64 * (it + 1)];
            b0 = pb0[64 * (it + 1)];
            b1 = pb1[64 * (it + 1)];
        }
    }

    f32x4* redv = (f32x4*)red;
    redv[(w * 4 + 0) * 64 + lane] = acc00;
    redv[(w * 4 + 1) * 64 + lane] = acc01;
    redv[(w * 4 + 2) * 64 + lane] = acc10;
    redv[(w * 4 + 3) * 64 + lane] = acc11;
    __syncthreads();

    #pragma unroll
    for (int half = 0; half < 2; ++half) {
        const int flat = half * 512 + tid;
        float sum = 0.f;
        #pragma unroll
        for (int w2 = 0; w2 < 8; ++w2) sum += red[w2 * 1024 + flat];
        const int f  = flat >> 8;
        const int l  = (flat >> 2) & 63;
        const int rr = flat & 3;
        const int row = m * 32 + (f >> 1) * 16 + ((l >> 4) << 2) + rr;
        const int col = n * 32 + (f & 1) * 16 + (l & 15);
        OUT[row * UNITS + col] = sum + BIAS[col];
    }
}

// ---------------- fallback (round-1 fused fp32, no workspace) ----------------
__global__ __launch_bounds__(256) void kan_fused(
    const float* __restrict__ X, const float* __restrict__ SK,
    const float* __restrict__ SF, const float* __restrict__ BIAS,
    float* __restrict__ OUT) {
    __shared__ float feat[128][12];
    const int tid  = threadIdx.x;
    const int brow = blockIdx.x * 4;
    const int o    = tid;
    float acc[4] = {0.f, 0.f, 0.f, 0.f};
    for (int c = 0; c < 8; ++c) {
        if (tid < 128) {
            const int ii = tid >> 2;
            const int r  = tid & 3;
            const int i  = c * 32 + ii;
            const float x = X[(size_t)(brow + r) * IN_DIM + i];
            float u = (x + 2.2f) * 2.5f;
            int j = (int)floorf(u);
            j = j < 3 ? 3 : (j > 7 ? 7 : j);
            const float gj = -2.2f + 0.4f * (float)j;
            const float t  = (x - gj) * 2.5f;
            const float t2 = t * t, t3 = t2 * t;
            const float k6 = 1.f / 6.f;
            float* fp = feat[ii * 4 + r];
            #pragma unroll
            for (int k = 0; k < 12; ++k) fp[k] = 0.f;
            const int base = j - 3;
            fp[base + 0] = (1.f - 3.f*t + 3.f*t2 - t3) * k6;
            fp[base + 1] = (3.f*t3 - 6.f*t2 + 4.f) * k6;
            fp[base + 2] = (-3.f*t3 + 3.f*t2 + 3.f*t + 1.f) * k6;
            fp[base + 3] = t3 * k6;
            fp[8] = x / (1.f + __expf(-x));
        }
        __syncthreads();
        #pragma unroll 4
        for (int ii = 0; ii < 32; ++ii) {
            const int i = c * 32 + ii;
            const float* skp = SK + (size_t)i * 8 * UNITS + o;
            const float s0 = skp[0*UNITS], s1 = skp[1*UNITS], s2 = skp[2*UNITS], s3 = skp[3*UNITS];
            const float s4 = skp[4*UNITS], s5 = skp[5*UNITS], s6 = skp[6*UNITS], s7 = skp[7*UNITS];
            const float sfv = SF[(size_t)i * UNITS + o];
            #pragma unroll
            for (int r = 0; r < 4; ++r) {
                const float* fp = feat[ii * 4 + r];
                const float4 fa = *(const float4*)(fp);
                const float4 fb = *(const float4*)(fp + 4);
                float ts = fp[8];
                ts = fmaf(fa.x, s0, ts); ts = fmaf(fa.y, s1, ts);
                ts = fmaf(fa.z, s2, ts); ts = fmaf(fa.w, s3, ts);
                ts = fmaf(fb.x, s4, ts); ts = fmaf(fb.y, s5, ts);
                ts = fmaf(fb.z, s6, ts); ts = fmaf(fb.w, s7, ts);
                acc[r] = fmaf(sfv, ts, acc[r]);
            }
        }
        __syncthreads();
    }
    const float bo = BIAS[o];
    #pragma unroll
    for (int r = 0; r < 4; ++r)
        OUT[(size_t)(brow + r) * UNITS + o] = acc[r] + bo;
}

extern "C" void kernel_launch(void* const* d_in, const int* in_sizes, int n_in,
                              void* d_out, int out_size, void* d_ws, size_t ws_size,
                              hipStream_t stream) {
    const float* X  = (const float*)d_in[0];
    const float* SK = (const float*)d_in[1];
    const float* SF = (const float*)d_in[2];
    const float* B  = (const float*)d_in[3];
    float* OUT = (float*)d_out;

    const size_t need = ((size_t)A_ELEMS + (size_t)W_ELEMS) * 2;   // 5,898,240 B
    if (d_ws != nullptr && ws_size >= need) {
        unsigned short* Ap = (unsigned short*)d_ws;
        unsigned short* Wp = Ap + A_ELEMS;
        prep_all<<<dim3(544), dim3(256), 0, stream>>>(X, SK, SF, Ap, Wp);
        kan_gemm<<<dim3(256), dim3(512), 0, stream>>>(Ap, Wp, B, OUT);
    } else {
        kan_fused<<<dim3(BATCH / 4), dim3(256), 0, stream>>>(X, SK, SF, B, OUT);
    }
}